// Round 11
// baseline (381.409 us; speedup 1.0000x reference)
//
#include <hip/hip_runtime.h>
#include <hip/hip_bf16.h>
#include <stdint.h>

// Problem: b=32, s=256, h=1024, 5 options.
// out = 0.5 * sum_n V_n @ o_n,  V_n = sum_{i!=n} softmax_k(q_i . o_k)_n,  q_i = o_i @ W
// bias is softmax-shift-invariant -> ignored.
// Round 11: r10's O-direct reverted (uncoalesced, -60%). gram rebuilt on
// mfma_32x32x16: doubles FLOP per LDS-read-byte (the measured r8 bound).
// 64x64 tile, 4 waves of 32x32 patches, 320-VGPR acc, 1 wave/SIMD,
// frag-ordered lane-linear LDS (conflict-free, no swizzle), r8's proven
// vmcnt(5)/3-buffer/1-barrier staging protocol over 64 K16-steps.

#define BB 32
#define SS 256
#define HH 1024

typedef __attribute__((ext_vector_type(4))) float f32x4;
typedef __attribute__((ext_vector_type(16))) float f32x16;
typedef __attribute__((ext_vector_type(8))) __bf16 bf16x8;
typedef __attribute__((ext_vector_type(4))) __bf16 bf16x4;

__device__ constexpr int PAIR(int i, int n) { return i * 4 + (n > i ? n - 1 : n); }

__device__ __forceinline__ void gload_lds16(const void* g, void* l) {
  __builtin_amdgcn_global_load_lds((const __attribute__((address_space(1))) void*)g,
                                   (__attribute__((address_space(3))) void*)l, 16, 0, 0);
}

__global__ void canary(float* out, float v) { out[0] = v; }

// ---------------------------------------------------------------------------
// fp32 -> bf16 flat cast of the 5 options into Obf[m][b][s][h].
__global__ __launch_bounds__(256) void cast_all(
    const float* p0, const float* p1, const float* p2, const float* p3, const float* p4,
    __bf16* __restrict__ dst)
{
  int m = blockIdx.x >> 12;
  long off = ((long)(blockIdx.x & 4095) * 256 + threadIdx.x) * 8;
  const float* src = m == 0 ? p0 : m == 1 ? p1 : m == 2 ? p2 : m == 3 ? p3 : p4;
  float4 v0 = *(const float4*)(src + off);
  float4 v1 = *(const float4*)(src + off + 4);
  bf16x8 h;
  h[0] = (__bf16)v0.x; h[1] = (__bf16)v0.y; h[2] = (__bf16)v0.z; h[3] = (__bf16)v0.w;
  h[4] = (__bf16)v1.x; h[5] = (__bf16)v1.y; h[6] = (__bf16)v1.z; h[7] = (__bf16)v1.w;
  *(bf16x8*)(dst + (long)m * BB * SS * HH + off) = h;
}

// ---------------------------------------------------------------------------
// W (1024x1024 fp32) -> Wt (bf16, transposed). 64x64 tiles, grid 256.
__global__ __launch_bounds__(256) void cast_trW(const float* __restrict__ src,
                                                __bf16* __restrict__ dstT)
{
  __shared__ __bf16 tile[64][72];
  int ct = blockIdx.x & 15, rt = blockIdx.x >> 4;
  const float* s = src + (long)(rt * 64) * 1024 + ct * 64;
  int t = threadIdx.x;
#pragma unroll
  for (int p = 0; p < 4; p++) {
    int c = t + p * 256;
    int row = c >> 4, c4 = c & 15;
    float4 v = *(const float4*)(s + (long)row * 1024 + c4 * 4);
    bf16x4 h;
    h[0] = (__bf16)v.x; h[1] = (__bf16)v.y; h[2] = (__bf16)v.z; h[3] = (__bf16)v.w;
    *(bf16x4*)&tile[row][c4 * 4] = h;
  }
  __syncthreads();
#pragma unroll
  for (int p = 0; p < 4; p++) {
    int c = t + p * 256;
    int hr = c >> 4, s4 = c & 15;
    bf16x4 h;
    h[0] = tile[s4 * 4 + 0][hr];
    h[1] = tile[s4 * 4 + 1][hr];
    h[2] = tile[s4 * 4 + 2][hr];
    h[3] = tile[s4 * 4 + 3][hr];
    *(bf16x4*)(dstT + (long)(ct * 64 + hr) * 1024 + rt * 64 + s4 * 4) = h;
  }
}

// ---------------------------------------------------------------------------
// qgemm: Q = Obf @ Wt. 128x128 tile, BK=32, XCD/L2 remap (grid 2560),
// 3-buffer counted-vmcnt pipeline + XOR swizzle (both sides) + setprio. (r8)
__global__ __launch_bounds__(256, 3) void qgemm_b16(
    const __bf16* __restrict__ A, const __bf16* __restrict__ Bt, __bf16* __restrict__ C)
{
  __shared__ __align__(16) char ldsb[3 * 16384];
  int lin = blockIdx.x;
  int xcd = lin & 7, idx = lin >> 3;
  int rt = xcd * 40 + (idx >> 3), ct = idx & 7;
  int t = threadIdx.x, l = t & 63, w = t >> 6;
  int wm = w >> 1, wn = w & 1;
  f32x4 acc[4][4] = {};

  const char *gA0, *gA1, *gB0, *gB1;
  {
    int c0 = t, c1 = t + 256;
    int r0 = c0 >> 2, h0 = (c0 & 3) ^ ((c0 >> 3) & 3);
    int r1 = c1 >> 2, h1 = (c1 & 3) ^ ((c1 >> 3) & 3);
    gA0 = (const char*)(A + (long)(rt * 128 + r0) * 1024 + h0 * 8);
    gA1 = (const char*)(A + (long)(rt * 128 + r1) * 1024 + h1 * 8);
    gB0 = (const char*)(Bt + (long)(ct * 128 + r0) * 1024 + h0 * 8);
    gB1 = (const char*)(Bt + (long)(ct * 128 + r1) * 1024 + h1 * 8);
  }
  int dst0 = w * 1024, dst1 = (w + 4) * 1024;

#define STAGE(BUF)                                                \
  {                                                               \
    char* base = ldsb + (BUF) * 16384;                            \
    gload_lds16(gA0, base + dst0); gA0 += 64;                     \
    gload_lds16(gA1, base + dst1); gA1 += 64;                     \
    gload_lds16(gB0, base + 8192 + dst0); gB0 += 64;              \
    gload_lds16(gB1, base + 8192 + dst1); gB1 += 64;              \
  }

  int lr = l & 15, sl = l >> 4;
  int swz = (sl ^ ((lr >> 1) & 3)) * 16;
  int aoff = (wm * 64 + lr) * 64 + swz;
  int boff = 8192 + (wn * 64 + lr) * 64 + swz;

#define COMPUTE(BUF)                                                                   \
  {                                                                                    \
    const char* base = ldsb + (BUF) * 16384;                                           \
    bf16x8 af[4], bfr[4];                                                              \
    _Pragma("unroll") for (int i = 0; i < 4; i++) {                                    \
      af[i]  = *(const bf16x8*)(base + aoff + i * 1024);                               \
      bfr[i] = *(const bf16x8*)(base + boff + i * 1024);                               \
    }                                                                                  \
    __builtin_amdgcn_s_setprio(1);                                                     \
    _Pragma("unroll") for (int i = 0; i < 4; i++)                                      \
      _Pragma("unroll") for (int j = 0; j < 4; j++)                                    \
        acc[i][j] = __builtin_amdgcn_mfma_f32_16x16x32_bf16(af[i], bfr[j],             \
                                                            acc[i][j], 0, 0, 0);       \
    __builtin_amdgcn_s_setprio(0);                                                     \
  }

#define STEP(CUR, STG)                                          \
  asm volatile("s_waitcnt vmcnt(4)" ::: "memory");              \
  __builtin_amdgcn_s_barrier();                                 \
  STAGE(STG);                                                   \
  COMPUTE(CUR);

  STAGE(0)
  STAGE(1)
  for (int it = 0; it < 10; it++) {
    STEP(0, 2)
    STEP(1, 0)
    STEP(2, 1)
  }
  asm volatile("s_waitcnt vmcnt(4)" ::: "memory");
  __builtin_amdgcn_s_barrier();
  COMPUTE(0)
  asm volatile("s_waitcnt vmcnt(0)" ::: "memory");
  __builtin_amdgcn_s_barrier();
  COMPUTE(1)
#undef STEP
#undef COMPUTE
#undef STAGE

#pragma unroll
  for (int i = 0; i < 4; i++) {
    long mrow = (long)rt * 128 + wm * 64 + i * 16 + ((l >> 4) << 2);
#pragma unroll
    for (int j = 0; j < 4; j++) {
      int n = ct * 128 + wn * 64 + j * 16 + (l & 15);
#pragma unroll
      for (int r = 0; r < 4; r++)
        C[(mrow + r) * 1024 + n] = (__bf16)acc[i][j][r];
    }
  }
}

// ---------------------------------------------------------------------------
// gram32: 20 cross-grams via 32x32x16 MFMA + lane-local softmax -> V.
// 64x64 tile, 4 waves (2x2 of 32x32). K16 steps; per step stage 20KB
// (5 uniform DMA/thread) into 3 rotating frag-ordered buffers.
// Buffer layout: [mq 0..9][ch 0..1][row 0..63][16B]; Q = mq<5, O base 10240.
// Frag read (wave pr,pc): lane-linear within two 512B spans -> conflict-free.
__global__ __launch_bounds__(256, 1) void gram32(
    const __bf16* __restrict__ Q, const __bf16* __restrict__ O, __bf16* __restrict__ V)
{
  __shared__ __align__(16) char ldsb[3 * 20480];  // 60 KB
  int bid = blockIdx.x;
  int xcd = bid & 7, idx = bid >> 3;   // 512 = 8 XCD x 64 (bijective)
  int b = xcd * 4 + (idx >> 4);        // 4 batches per XCD
  int rem = idx & 15;
  int s1t = rem >> 2, s2t = rem & 3;   // s1t-major within batch
  int t = threadIdx.x, l = t & 63, w = t >> 6;
  int pr = w >> 1, pc = w & 1;
  f32x16 acc[20] = {};

  // staging: thread t, p=0..4: chunk c = t + 256p; mq=c>>7, ch=(c>>6)&1, row=c&63.
  // LDS dst (wave base; HW adds lane*16) = ((t&~63) + 256p)*16.
  const char* gp[5];
  int udst[5];
#pragma unroll
  for (int p = 0; p < 5; p++) {
    int c = t + 256 * p;
    int mq = c >> 7, ch = (c >> 6) & 1, row = c & 63;
    long grow = mq < 5 ? ((long)mq * (BB * SS) + (long)b * SS + s1t * 64 + row)
                       : ((long)(mq - 5) * (BB * SS) + (long)b * SS + s2t * 64 + row);
    gp[p] = (const char*)(mq < 5 ? Q : O) + grow * (HH * 2) + ch * 16;
    udst[p] = ((t & ~63) + 256 * p) * 16;
  }

  // frag-read offsets: qf[m] @ m*2048 + (l>>5)*1024 + (pr*32 + (l&31))*16
  int qro = (l >> 5) * 1024 + (pr * 32 + (l & 31)) * 16;
  int oro = 10240 + (l >> 5) * 1024 + (pc * 32 + (l & 31)) * 16;

#define QSTAGE(BUF)                                                     \
  {                                                                     \
    char* base = ldsb + (BUF) * 20480;                                  \
    _Pragma("unroll") for (int p = 0; p < 5; p++) {                     \
      gload_lds16(gp[p], base + udst[p]);                               \
      gp[p] += 32;                                                      \
    }                                                                   \
  }

#define MFMA_STEP(BUF)                                                                 \
  {                                                                                    \
    const char* base = ldsb + (BUF) * 20480;                                           \
    bf16x8 qf[5], of[5];                                                               \
    _Pragma("unroll") for (int m = 0; m < 5; m++) {                                    \
      qf[m] = *(const bf16x8*)(base + m * 2048 + qro);                                 \
      of[m] = *(const bf16x8*)(base + m * 2048 + oro);                                 \
    }                                                                                  \
    __builtin_amdgcn_s_setprio(1);                                                     \
    _Pragma("unroll") for (int i = 0; i < 5; i++) {                                    \
      _Pragma("unroll") for (int n = 0; n < 5; n++) {                                  \
        if (n != i)                                                                    \
          acc[PAIR(i, n)] = __builtin_amdgcn_mfma_f32_32x32x16_bf16(                   \
              qf[i], of[n], acc[PAIR(i, n)], 0, 0, 0);                                 \
      }                                                                                \
    }                                                                                  \
    __builtin_amdgcn_s_setprio(0);                                                     \
  }

#define STEP(CUR, STG)                                          \
  asm volatile("s_waitcnt vmcnt(5)" ::: "memory");              \
  __builtin_amdgcn_s_barrier();                                 \
  QSTAGE(STG);                                                  \
  MFMA_STEP(CUR);

  QSTAGE(0)
  QSTAGE(1)
  for (int it = 0; it < 20; it++) {  // K16-steps 0..59, staging 2..61
    STEP(0, 2)
    STEP(1, 0)
    STEP(2, 1)
  }
  STEP(0, 2)  // step 60, stage 62
  STEP(1, 0)  // step 61, stage 63
  asm volatile("s_waitcnt vmcnt(5)" ::: "memory");  // step 62
  __builtin_amdgcn_s_barrier();
  MFMA_STEP(2)
  asm volatile("s_waitcnt vmcnt(0)" ::: "memory");  // step 63
  __builtin_amdgcn_s_barrier();
  MFMA_STEP(0)
#undef STEP
#undef MFMA_STEP
#undef QSTAGE

  // epilogue: lane-local softmax over n (4 live options per i), sum into V_n.
  // C layout 32x32: col = l&31, row = (r&3) + 8*(r>>2) + 4*(l>>5).
  int s2g = s2t * 64 + pc * 32 + (l & 31);
  int s1b = s1t * 64 + pr * 32 + 4 * (l >> 5);
#pragma unroll
  for (int r = 0; r < 16; r++) {
    int s1 = s1b + (r & 3) + 8 * (r >> 2);
    float vacc[5] = {0.f, 0.f, 0.f, 0.f, 0.f};
#pragma unroll
    for (int i = 0; i < 5; i++) {
      float gg[5];
      float mx = -3.0e38f;
#pragma unroll
      for (int n = 0; n < 5; n++)
        if (n != i) { gg[n] = acc[PAIR(i, n)][r]; mx = fmaxf(mx, gg[n]); }
      float ee[5], ssum = 0.f;
#pragma unroll
      for (int n = 0; n < 5; n++)
        if (n != i) { ee[n] = __expf(gg[n] - mx); ssum += ee[n]; }
      float inv = 1.0f / ssum;
#pragma unroll
      for (int n = 0; n < 5; n++)
        if (n != i) vacc[n] += ee[n] * inv;
    }
#pragma unroll
    for (int n = 0; n < 5; n++)
      V[((long)(n * BB + b) * SS + s1) * SS + s2g] = (__bf16)vacc[n];
  }
}

// ---------------------------------------------------------------------------
// out = 0.5 * sum_n V_n @ o_n (per batch). A: V rows (bf16, s2-contig).
// B: Obf bf16 (s2 x h), transposed in LDS via 4x4 register sub-blocks.
__global__ __launch_bounds__(256) void pvgemm(
    const __bf16* __restrict__ Vb, const __bf16* __restrict__ Obf, float* __restrict__ out)
{
  __shared__ __bf16 smA[128][40];
  __shared__ __bf16 smB[128][40];
  int bid = blockIdx.x;
  int b = bid >> 4, s1t = (bid >> 3) & 1, ht = bid & 7;
  int t = threadIdx.x, l = t & 63, w = t >> 6;
  int wm = w >> 1, wn = w & 1;
  f32x4 acc[4][4] = {};
#pragma unroll
  for (int n = 0; n < 5; n++) {
    const __bf16* On = Obf + (long)n * BB * SS * HH;
    for (int st2 = 0; st2 < 8; st2++) {
      int s20 = st2 * 32;
#pragma unroll
      for (int p = 0; p < 2; p++) {
        int c = t + p * 256;
        int row = c >> 2, sl = c & 3;
        *(bf16x8*)&smA[row][sl * 8] =
            *(const bf16x8*)(Vb + (long)(n * BB + b) * SS * SS + (long)(s1t * 128 + row) * SS +
                             s20 + sl * 8);
      }
      {
        int h4 = (t & 31) * 4, s2q = (t >> 5) * 4;
        const __bf16* src = On + ((long)b * 256 + s20 + s2q) * 1024 + ht * 128 + h4;
        bf16x4 v0 = *(const bf16x4*)(src);
        bf16x4 v1 = *(const bf16x4*)(src + 1024);
        bf16x4 v2 = *(const bf16x4*)(src + 2048);
        bf16x4 v3 = *(const bf16x4*)(src + 3072);
        bf16x4 c0, c1, c2, c3;
        c0[0] = v0[0]; c0[1] = v1[0]; c0[2] = v2[0]; c0[3] = v3[0];
        c1[0] = v0[1]; c1[1] = v1[1]; c1[2] = v2[1]; c1[3] = v3[1];
        c2[0] = v0[2]; c2[1] = v1[2]; c2[2] = v2[2]; c2[3] = v3[2];
        c3[0] = v0[3]; c3[1] = v1[3]; c3[2] = v2[3]; c3[3] = v3[3];
        *(bf16x4*)&smB[h4 + 0][s2q] = c0;
        *(bf16x4*)&smB[h4 + 1][s2q] = c1;
        *(bf16x4*)&smB[h4 + 2][s2q] = c2;
        *(bf16x4*)&smB[h4 + 3][s2q] = c3;
      }
      __syncthreads();
      bf16x8 af[4], bfr[4];
      int sl = l >> 4, lr = l & 15;
#pragma unroll
      for (int i = 0; i < 4; i++) {
        af[i]  = *(const bf16x8*)&smA[wm * 64 + i * 16 + lr][sl * 8];
        bfr[i] = *(const bf16x8*)&smB[wn * 64 + i * 16 + lr][sl * 8];
      }
#pragma unroll
      for (int i = 0; i < 4; i++)
#pragma unroll
        for (int j = 0; j < 4; j++)
          acc[i][j] = __builtin_amdgcn_mfma_f32_16x16x32_bf16(af[i], bfr[j], acc[i][j], 0, 0, 0);
      __syncthreads();
    }
  }
#pragma unroll
  for (int i = 0; i < 4; i++) {
    int m = s1t * 128 + wm * 64 + i * 16 + ((l >> 4) << 2);
#pragma unroll
    for (int j = 0; j < 4; j++) {
      int n = ht * 128 + wn * 64 + j * 16 + (l & 15);
#pragma unroll
      for (int r = 0; r < 4; r++)
        out[(long)(b * SS + m + r) * HH + n] = 0.5f * acc[i][j][r];
    }
  }
}

// ---------------------------------------------------------------------------
extern "C" void kernel_launch(void* const* d_in, const int* in_sizes, int n_in,
                              void* d_out, int out_size, void* d_ws, size_t ws_size,
                              hipStream_t stream)
{
  const size_t SZ_W = (size_t)HH * HH * 2;           //  2 MB
  const size_t SZ_Q = (size_t)5 * BB * SS * HH * 2;  // 84 MB
  const size_t SZ_V = (size_t)5 * BB * SS * SS * 2;  // 21 MB
  const size_t SZ_O = (size_t)5 * BB * SS * HH * 2;  // 84 MB
  const size_t NEED = SZ_W + SZ_Q + SZ_V + SZ_O;     // 191 MB (proven available r4)
  if (ws_size < NEED) {
    canary<<<1, 1, 0, stream>>>((float*)d_out, (float)(ws_size >> 20));
    return;
  }
  char* ws = (char*)d_ws;
  __bf16* Wt  = (__bf16*)ws;
  __bf16* Qb  = (__bf16*)(ws + SZ_W);
  __bf16* Vb  = (__bf16*)(ws + SZ_W + SZ_Q);
  __bf16* Obf = (__bf16*)(ws + SZ_W + SZ_Q + SZ_V);
  const float* o0 = (const float*)d_in[0];
  const float* o1 = (const float*)d_in[1];
  const float* o2 = (const float*)d_in[2];
  const float* o3 = (const float*)d_in[3];
  const float* o4 = (const float*)d_in[4];

  cast_trW<<<256, 256, 0, stream>>>((const float*)d_in[5], Wt);
  cast_all<<<5 * 4096, 256, 0, stream>>>(o0, o1, o2, o3, o4, Obf);
  qgemm_b16<<<2560, 256, 0, stream>>>(Obf, Wt, Qb);
  gram32<<<512, 256, 0, stream>>>(Qb, Obf, Vb);
  pvgemm<<<512, 256, 0, stream>>>(Vb, Obf, (float*)d_out);
}

// Round 12
// 280.341 us; speedup vs baseline: 1.3605x; 1.3605x over previous
//
#include <hip/hip_runtime.h>
#include <hip/hip_bf16.h>
#include <stdint.h>

// Problem: b=32, s=256, h=1024, 5 options.
// out = 0.5 * sum_n V_n @ o_n,  V_n = sum_{i!=n} softmax_k(q_i . o_k)_n,  q_i = o_i @ W
// bias is softmax-shift-invariant -> ignored.
// Round 12: gram32 spilled (VGPR cap 256, WRITE_SIZE 111MB) -> reverted to the
// r8-proven gram_b16 (117us). qgemm upgraded to 256x256 tile / 512 thr / 8
// waves (128x64 each): per-output LDS bytes 3->2 B/pt/Kstep. Same proven
// 3-buffer counted-vmcnt protocol + XOR swizzle.

#define BB 32
#define SS 256
#define HH 1024

typedef __attribute__((ext_vector_type(4))) float f32x4;
typedef __attribute__((ext_vector_type(8))) __bf16 bf16x8;
typedef __attribute__((ext_vector_type(4))) __bf16 bf16x4;

__device__ constexpr int PAIR(int i, int n) { return i * 4 + (n > i ? n - 1 : n); }

__device__ __forceinline__ void gload_lds16(const void* g, void* l) {
  __builtin_amdgcn_global_load_lds((const __attribute__((address_space(1))) void*)g,
                                   (__attribute__((address_space(3))) void*)l, 16, 0, 0);
}

__global__ void canary(float* out, float v) { out[0] = v; }

// ---------------------------------------------------------------------------
// fp32 -> bf16 flat cast of the 5 options into Obf[m][b][s][h].
__global__ __launch_bounds__(256) void cast_all(
    const float* p0, const float* p1, const float* p2, const float* p3, const float* p4,
    __bf16* __restrict__ dst)
{
  int m = blockIdx.x >> 12;
  long off = ((long)(blockIdx.x & 4095) * 256 + threadIdx.x) * 8;
  const float* src = m == 0 ? p0 : m == 1 ? p1 : m == 2 ? p2 : m == 3 ? p3 : p4;
  float4 v0 = *(const float4*)(src + off);
  float4 v1 = *(const float4*)(src + off + 4);
  bf16x8 h;
  h[0] = (__bf16)v0.x; h[1] = (__bf16)v0.y; h[2] = (__bf16)v0.z; h[3] = (__bf16)v0.w;
  h[4] = (__bf16)v1.x; h[5] = (__bf16)v1.y; h[6] = (__bf16)v1.z; h[7] = (__bf16)v1.w;
  *(bf16x8*)(dst + (long)m * BB * SS * HH + off) = h;
}

// ---------------------------------------------------------------------------
// W (1024x1024 fp32) -> Wt (bf16, transposed). 64x64 tiles, grid 256.
__global__ __launch_bounds__(256) void cast_trW(const float* __restrict__ src,
                                                __bf16* __restrict__ dstT)
{
  __shared__ __bf16 tile[64][72];
  int ct = blockIdx.x & 15, rt = blockIdx.x >> 4;
  const float* s = src + (long)(rt * 64) * 1024 + ct * 64;
  int t = threadIdx.x;
#pragma unroll
  for (int p = 0; p < 4; p++) {
    int c = t + p * 256;
    int row = c >> 4, c4 = c & 15;
    float4 v = *(const float4*)(s + (long)row * 1024 + c4 * 4);
    bf16x4 h;
    h[0] = (__bf16)v.x; h[1] = (__bf16)v.y; h[2] = (__bf16)v.z; h[3] = (__bf16)v.w;
    *(bf16x4*)&tile[row][c4 * 4] = h;
  }
  __syncthreads();
#pragma unroll
  for (int p = 0; p < 4; p++) {
    int c = t + p * 256;
    int hr = c >> 4, s4 = c & 15;
    bf16x4 h;
    h[0] = tile[s4 * 4 + 0][hr];
    h[1] = tile[s4 * 4 + 1][hr];
    h[2] = tile[s4 * 4 + 2][hr];
    h[3] = tile[s4 * 4 + 3][hr];
    *(bf16x4*)(dstT + (long)(ct * 64 + hr) * 1024 + rt * 64 + s4 * 4) = h;
  }
}

// ---------------------------------------------------------------------------
// qgemm256: Q = Obf @ Wt. 256x256 tile, 512 thr, 8 waves (2x4; wave 128x64),
// BK=32, 3-buffer counted-vmcnt pipeline + XOR swizzle + setprio.
// Grid 640 = 8 XCD x (20 rt x 4 ct), ct-inner for A-slab L2 reuse.
__global__ __launch_bounds__(512, 2) void qgemm256(
    const __bf16* __restrict__ A, const __bf16* __restrict__ Bt, __bf16* __restrict__ C)
{
  __shared__ __align__(16) char ldsb[3 * 32768];  // 96 KB: per buf A[16K] B[16K]
  int lin = blockIdx.x;
  int xcd = lin & 7, idx = lin >> 3;         // 640 = 8 x 80 (bijective)
  int rt = xcd * 20 + (idx >> 2), ct = idx & 3;
  int t = threadIdx.x, l = t & 63, w = t >> 6;
  int wr = w >> 2, wc = w & 3;               // wave patch: 128 x 64
  f32x4 acc[8][4] = {};

  // staging: thread t owns chunks c = t + 512p, p=0..3 (p<2: A, else B).
  // chunk c (within half): row = c>>2, slot = c&3, swizzled slot' = slot^((row>>1)&3).
  const char* gp[4];
  int dstp[4];
#pragma unroll
  for (int p = 0; p < 4; p++) {
    int c = t + 512 * p;
    int ch = c & 1023;                       // chunk within A- or B-half
    int row = ch >> 2;
    int sl2 = (ch & 3) ^ ((ch >> 3) & 3);
    if (p < 2)
      gp[p] = (const char*)(A + (long)(rt * 256 + row) * 1024 + sl2 * 8);
    else
      gp[p] = (const char*)(Bt + (long)(ct * 256 + row) * 1024 + sl2 * 8);
    dstp[p] = (w + 8 * p) << 10;             // wave-uniform 1KB groups; B at +16KB
  }

#define STAGE(BUF)                                                \
  {                                                               \
    char* base = ldsb + (BUF) * 32768;                            \
    _Pragma("unroll") for (int p = 0; p < 4; p++) {               \
      gload_lds16(gp[p], base + dstp[p]);                         \
      gp[p] += 64;                                                \
    }                                                             \
  }

  int lr = l & 15, sl = l >> 4;
  int swz = (sl ^ ((lr >> 1) & 3)) * 16;
  int aoff = (wr * 128 + lr) * 64 + swz;           // + fi*1024
  int boff = 16384 + (wc * 64 + lr) * 64 + swz;    // + fj*1024

#define COMPUTE(BUF)                                                                   \
  {                                                                                    \
    const char* base = ldsb + (BUF) * 32768;                                           \
    bf16x8 af[8], bfr[4];                                                              \
    _Pragma("unroll") for (int i = 0; i < 8; i++)                                      \
      af[i] = *(const bf16x8*)(base + aoff + i * 1024);                                \
    _Pragma("unroll") for (int j = 0; j < 4; j++)                                      \
      bfr[j] = *(const bf16x8*)(base + boff + j * 1024);                               \
    __builtin_amdgcn_s_setprio(1);                                                     \
    _Pragma("unroll") for (int i = 0; i < 8; i++)                                      \
      _Pragma("unroll") for (int j = 0; j < 4; j++)                                    \
        acc[i][j] = __builtin_amdgcn_mfma_f32_16x16x32_bf16(af[i], bfr[j],             \
                                                            acc[i][j], 0, 0, 0);       \
    __builtin_amdgcn_s_setprio(0);                                                     \
  }

#define STEP(CUR, STG)                                          \
  asm volatile("s_waitcnt vmcnt(4)" ::: "memory");              \
  __builtin_amdgcn_s_barrier();                                 \
  STAGE(STG);                                                   \
  COMPUTE(CUR);

  STAGE(0)
  STAGE(1)
  for (int it = 0; it < 10; it++) {  // K-steps 0..29, staging 2..31
    STEP(0, 2)
    STEP(1, 0)
    STEP(2, 1)
  }
  asm volatile("s_waitcnt vmcnt(4)" ::: "memory");  // K-step 30
  __builtin_amdgcn_s_barrier();
  COMPUTE(0)
  asm volatile("s_waitcnt vmcnt(0)" ::: "memory");  // K-step 31
  __builtin_amdgcn_s_barrier();
  COMPUTE(1)
#undef STEP
#undef COMPUTE
#undef STAGE

#pragma unroll
  for (int i = 0; i < 8; i++) {
    long mrow = (long)rt * 256 + wr * 128 + i * 16 + (sl << 2);
#pragma unroll
    for (int j = 0; j < 4; j++) {
      int n = ct * 256 + wc * 64 + j * 16 + lr;
#pragma unroll
      for (int r = 0; r < 4; r++)
        C[(mrow + r) * 1024 + n] = (__bf16)acc[i][j][r];
    }
  }
}

// ---------------------------------------------------------------------------
// gram: 20 cross-grams + lane-local softmax -> V. (r8-proven, 117us)
__global__ __launch_bounds__(256, 2) void gram_b16(
    const __bf16* __restrict__ Q, const __bf16* __restrict__ O, __bf16* __restrict__ V)
{
  __shared__ __align__(16) char ldsb[3 * 20480];  // 60 KB
  int bid = blockIdx.x;
  int xcd = bid & 7, idx = bid >> 3;          // 2048 = 8 XCD x 256 (bijective)
  int b = xcd * 4 + (idx >> 6);               // 4 batches per XCD
  int rem = idx & 63;
  int s1t = rem >> 3, s2t = rem & 7;          // s1t-major within batch
  int t = threadIdx.x, l = t & 63, w = t >> 6;
  int pr = w >> 1, pc = w & 1;
  f32x4 acc[20] = {};

  long qrow0 = (long)b * SS + s1t * 32;
  long orow0 = (long)b * SS + s2t * 32;
  int slog = (l & 3) ^ ((l >> 3) & 3);
  const char* gp0; const char* gp1; const char* gp2; const char* gp3; const char* gp4;
#define GP_INIT(GP, P)                                                                \
  {                                                                                   \
    int g = 4 * (P) + w;                                                              \
    int isQ = g < 10;                                                                 \
    int gg = isQ ? g : g - 10;                                                        \
    long row = (long)(gg >> 1) * (BB * SS) + (isQ ? qrow0 : orow0) + (g & 1) * 16 +   \
               (l >> 2);                                                              \
    GP = (const char*)((isQ ? Q : O) + row * HH + slog * 8);                          \
  }
  GP_INIT(gp0, 0) GP_INIT(gp1, 1) GP_INIT(gp2, 2) GP_INIT(gp3, 3) GP_INIT(gp4, 4)
#undef GP_INIT
  int g0 = w, g1 = 4 + w, g2 = 8 + w, g3 = 12 + w, g4 = 16 + w;

#define STAGE(BB_)                                                      \
  {                                                                     \
    char* base = ldsb + (BB_) * 20480;                                  \
    gload_lds16(gp0, base + g0 * 1024); gp0 += 64;                      \
    gload_lds16(gp1, base + g1 * 1024); gp1 += 64;                      \
    gload_lds16(gp2, base + g2 * 1024); gp2 += 64;                      \
    gload_lds16(gp3, base + g3 * 1024); gp3 += 64;                      \
    gload_lds16(gp4, base + g4 * 1024); gp4 += 64;                      \
  }

  int lr = l & 15, sl = l >> 4;
  int swz = (sl ^ ((lr >> 1) & 3)) * 16;
  int qoff = (pr * 16 + lr) * 64 + swz;
  int ooff = 10240 + (pc * 16 + lr) * 64 + swz;

#define COMPUTE(BB_)                                                                   \
  {                                                                                    \
    const char* base = ldsb + (BB_) * 20480;                                           \
    bf16x8 qf[5], of[5];                                                               \
    _Pragma("unroll") for (int m = 0; m < 5; m++) {                                    \
      qf[m] = *(const bf16x8*)(base + m * 2048 + qoff);                                \
      of[m] = *(const bf16x8*)(base + m * 2048 + ooff);                                \
    }                                                                                  \
    __builtin_amdgcn_s_setprio(1);                                                     \
    _Pragma("unroll") for (int i = 0; i < 5; i++) {                                    \
      _Pragma("unroll") for (int n = 0; n < 5; n++) {                                  \
        if (n != i)                                                                    \
          acc[PAIR(i, n)] =                                                            \
              __builtin_amdgcn_mfma_f32_16x16x32_bf16(qf[i], of[n], acc[PAIR(i, n)],   \
                                                      0, 0, 0);                        \
      }                                                                                \
    }                                                                                  \
    __builtin_amdgcn_s_setprio(0);                                                     \
  }

#define STEP(CUR, STG)                                          \
  asm volatile("s_waitcnt vmcnt(5)" ::: "memory");              \
  __builtin_amdgcn_s_barrier();                                 \
  STAGE(STG);                                                   \
  COMPUTE(CUR);

  STAGE(0)
  STAGE(1)
  for (int it = 0; it < 10; it++) {
    STEP(0, 2)
    STEP(1, 0)
    STEP(2, 1)
  }
  asm volatile("s_waitcnt vmcnt(5)" ::: "memory");
  __builtin_amdgcn_s_barrier();
  COMPUTE(0)
  asm volatile("s_waitcnt vmcnt(0)" ::: "memory");
  __builtin_amdgcn_s_barrier();
  COMPUTE(1)
#undef STEP
#undef COMPUTE
#undef STAGE

  int s1g = s1t * 32 + pr * 16 + ((l >> 4) << 2);
  int s2g = s2t * 32 + pc * 16 + (l & 15);
#pragma unroll
  for (int r = 0; r < 4; r++) {
    float vacc[5] = {0.f, 0.f, 0.f, 0.f, 0.f};
#pragma unroll
    for (int i = 0; i < 5; i++) {
      float gg[5];
      float mx = -3.0e38f;
#pragma unroll
      for (int n = 0; n < 5; n++)
        if (n != i) { gg[n] = acc[PAIR(i, n)][r]; mx = fmaxf(mx, gg[n]); }
      float ee[5], ssum = 0.f;
#pragma unroll
      for (int n = 0; n < 5; n++)
        if (n != i) { ee[n] = __expf(gg[n] - mx); ssum += ee[n]; }
      float inv = 1.0f / ssum;
#pragma unroll
      for (int n = 0; n < 5; n++)
        if (n != i) vacc[n] += ee[n] * inv;
    }
#pragma unroll
    for (int n = 0; n < 5; n++)
      V[((long)(n * 32 + b) * 256 + s1g + r) * 256 + s2g] = (__bf16)vacc[n];
  }
}

// ---------------------------------------------------------------------------
// out = 0.5 * sum_n V_n @ o_n (per batch). A: V rows (bf16, s2-contig).
// B: Obf bf16 (s2 x h), transposed in LDS via 4x4 register sub-blocks.
__global__ __launch_bounds__(256) void pvgemm(
    const __bf16* __restrict__ Vb, const __bf16* __restrict__ Obf, float* __restrict__ out)
{
  __shared__ __bf16 smA[128][40];
  __shared__ __bf16 smB[128][40];
  int bid = blockIdx.x;
  int b = bid >> 4, s1t = (bid >> 3) & 1, ht = bid & 7;
  int t = threadIdx.x, l = t & 63, w = t >> 6;
  int wm = w >> 1, wn = w & 1;
  f32x4 acc[4][4] = {};
#pragma unroll
  for (int n = 0; n < 5; n++) {
    const __bf16* On = Obf + (long)n * BB * SS * HH;
    for (int st2 = 0; st2 < 8; st2++) {
      int s20 = st2 * 32;
#pragma unroll
      for (int p = 0; p < 2; p++) {
        int c = t + p * 256;
        int row = c >> 2, sl = c & 3;
        *(bf16x8*)&smA[row][sl * 8] =
            *(const bf16x8*)(Vb + (long)(n * BB + b) * SS * SS + (long)(s1t * 128 + row) * SS +
                             s20 + sl * 8);
      }
      {
        int h4 = (t & 31) * 4, s2q = (t >> 5) * 4;
        const __bf16* src = On + ((long)b * 256 + s20 + s2q) * 1024 + ht * 128 + h4;
        bf16x4 v0 = *(const bf16x4*)(src);
        bf16x4 v1 = *(const bf16x4*)(src + 1024);
        bf16x4 v2 = *(const bf16x4*)(src + 2048);
        bf16x4 v3 = *(const bf16x4*)(src + 3072);
        bf16x4 c0, c1, c2, c3;
        c0[0] = v0[0]; c0[1] = v1[0]; c0[2] = v2[0]; c0[3] = v3[0];
        c1[0] = v0[1]; c1[1] = v1[1]; c1[2] = v2[1]; c1[3] = v3[1];
        c2[0] = v0[2]; c2[1] = v1[2]; c2[2] = v2[2]; c2[3] = v3[2];
        c3[0] = v0[3]; c3[1] = v1[3]; c3[2] = v2[3]; c3[3] = v3[3];
        *(bf16x4*)&smB[h4 + 0][s2q] = c0;
        *(bf16x4*)&smB[h4 + 1][s2q] = c1;
        *(bf16x4*)&smB[h4 + 2][s2q] = c2;
        *(bf16x4*)&smB[h4 + 3][s2q] = c3;
      }
      __syncthreads();
      bf16x8 af[4], bfr[4];
      int sl = l >> 4, lr = l & 15;
#pragma unroll
      for (int i = 0; i < 4; i++) {
        af[i]  = *(const bf16x8*)&smA[wm * 64 + i * 16 + lr][sl * 8];
        bfr[i] = *(const bf16x8*)&smB[wn * 64 + i * 16 + lr][sl * 8];
      }
#pragma unroll
      for (int i = 0; i < 4; i++)
#pragma unroll
        for (int j = 0; j < 4; j++)
          acc[i][j] = __builtin_amdgcn_mfma_f32_16x16x32_bf16(af[i], bfr[j], acc[i][j], 0, 0, 0);
      __syncthreads();
    }
  }
#pragma unroll
  for (int i = 0; i < 4; i++) {
    int m = s1t * 128 + wm * 64 + i * 16 + ((l >> 4) << 2);
#pragma unroll
    for (int j = 0; j < 4; j++) {
      int n = ht * 128 + wn * 64 + j * 16 + (l & 15);
#pragma unroll
      for (int r = 0; r < 4; r++)
        out[(long)(b * SS + m + r) * HH + n] = 0.5f * acc[i][j][r];
    }
  }
}

// ---------------------------------------------------------------------------
extern "C" void kernel_launch(void* const* d_in, const int* in_sizes, int n_in,
                              void* d_out, int out_size, void* d_ws, size_t ws_size,
                              hipStream_t stream)
{
  const size_t SZ_W = (size_t)HH * HH * 2;           //  2 MB
  const size_t SZ_Q = (size_t)5 * BB * SS * HH * 2;  // 84 MB
  const size_t SZ_V = (size_t)5 * BB * SS * SS * 2;  // 21 MB
  const size_t SZ_O = (size_t)5 * BB * SS * HH * 2;  // 84 MB
  const size_t NEED = SZ_W + SZ_Q + SZ_V + SZ_O;     // 191 MB (proven available r4)
  if (ws_size < NEED) {
    canary<<<1, 1, 0, stream>>>((float*)d_out, (float)(ws_size >> 20));
    return;
  }
  char* ws = (char*)d_ws;
  __bf16* Wt  = (__bf16*)ws;
  __bf16* Qb  = (__bf16*)(ws + SZ_W);
  __bf16* Vb  = (__bf16*)(ws + SZ_W + SZ_Q);
  __bf16* Obf = (__bf16*)(ws + SZ_W + SZ_Q + SZ_V);
  const float* o0 = (const float*)d_in[0];
  const float* o1 = (const float*)d_in[1];
  const float* o2 = (const float*)d_in[2];
  const float* o3 = (const float*)d_in[3];
  const float* o4 = (const float*)d_in[4];

  cast_trW<<<256, 256, 0, stream>>>((const float*)d_in[5], Wt);
  cast_all<<<5 * 4096, 256, 0, stream>>>(o0, o1, o2, o3, o4, Obf);
  qgemm256<<<640, 512, 0, stream>>>(Obf, Wt, Qb);
  gram_b16<<<2048, 256, 0, stream>>>(Qb, Obf, Vb);
  pvgemm<<<512, 256, 0, stream>>>(Vb, Obf, (float*)d_out);
}

// Round 13
// 279.937 us; speedup vs baseline: 1.3625x; 1.0014x over previous
//
#include <hip/hip_runtime.h>
#include <hip/hip_bf16.h>
#include <stdint.h>

// Problem: b=32, s=256, h=1024, 5 options.
// out = 0.5 * sum_n V_n @ o_n,  V_n = sum_{i!=n} softmax_k(q_i . o_k)_n,  q_i = o_i @ W
// bias is softmax-shift-invariant -> ignored.
// Round 13: qgemm256 -> BK=64, 2x64KB dbuf (m201 128KB-LDS regime), 4-phase
// interleave, ONE vmcnt(0)+barrier per K-tile (16 vs 32 sync points; drain
// hidden under ~800cyc of compute). 8-slot XOR swizzle both sides.
// gram (r8-proven 117us) / pvgemm / casts frozen.

#define BB 32
#define SS 256
#define HH 1024

typedef __attribute__((ext_vector_type(4))) float f32x4;
typedef __attribute__((ext_vector_type(8))) __bf16 bf16x8;
typedef __attribute__((ext_vector_type(4))) __bf16 bf16x4;

__device__ constexpr int PAIR(int i, int n) { return i * 4 + (n > i ? n - 1 : n); }

__device__ __forceinline__ void gload_lds16(const void* g, void* l) {
  __builtin_amdgcn_global_load_lds((const __attribute__((address_space(1))) void*)g,
                                   (__attribute__((address_space(3))) void*)l, 16, 0, 0);
}

__global__ void canary(float* out, float v) { out[0] = v; }

// ---------------------------------------------------------------------------
// fp32 -> bf16 flat cast of the 5 options into Obf[m][b][s][h].
__global__ __launch_bounds__(256) void cast_all(
    const float* p0, const float* p1, const float* p2, const float* p3, const float* p4,
    __bf16* __restrict__ dst)
{
  int m = blockIdx.x >> 12;
  long off = ((long)(blockIdx.x & 4095) * 256 + threadIdx.x) * 8;
  const float* src = m == 0 ? p0 : m == 1 ? p1 : m == 2 ? p2 : m == 3 ? p3 : p4;
  float4 v0 = *(const float4*)(src + off);
  float4 v1 = *(const float4*)(src + off + 4);
  bf16x8 h;
  h[0] = (__bf16)v0.x; h[1] = (__bf16)v0.y; h[2] = (__bf16)v0.z; h[3] = (__bf16)v0.w;
  h[4] = (__bf16)v1.x; h[5] = (__bf16)v1.y; h[6] = (__bf16)v1.z; h[7] = (__bf16)v1.w;
  *(bf16x8*)(dst + (long)m * BB * SS * HH + off) = h;
}

// ---------------------------------------------------------------------------
// W (1024x1024 fp32) -> Wt (bf16, transposed). 64x64 tiles, grid 256.
__global__ __launch_bounds__(256) void cast_trW(const float* __restrict__ src,
                                                __bf16* __restrict__ dstT)
{
  __shared__ __bf16 tile[64][72];
  int ct = blockIdx.x & 15, rt = blockIdx.x >> 4;
  const float* s = src + (long)(rt * 64) * 1024 + ct * 64;
  int t = threadIdx.x;
#pragma unroll
  for (int p = 0; p < 4; p++) {
    int c = t + p * 256;
    int row = c >> 4, c4 = c & 15;
    float4 v = *(const float4*)(s + (long)row * 1024 + c4 * 4);
    bf16x4 h;
    h[0] = (__bf16)v.x; h[1] = (__bf16)v.y; h[2] = (__bf16)v.z; h[3] = (__bf16)v.w;
    *(bf16x4*)&tile[row][c4 * 4] = h;
  }
  __syncthreads();
#pragma unroll
  for (int p = 0; p < 4; p++) {
    int c = t + p * 256;
    int hr = c >> 4, s4 = c & 15;
    bf16x4 h;
    h[0] = tile[s4 * 4 + 0][hr];
    h[1] = tile[s4 * 4 + 1][hr];
    h[2] = tile[s4 * 4 + 2][hr];
    h[3] = tile[s4 * 4 + 3][hr];
    *(bf16x4*)(dstT + (long)(ct * 64 + hr) * 1024 + rt * 64 + s4 * 4) = h;
  }
}

// ---------------------------------------------------------------------------
// qgemm256 v2: Q = Obf @ Wt. 256x256 tile, 512 thr, 8 waves (2x4; wave 128x64),
// BK=64, 2x64KB double-buffer, 4-phase interleave, one vmcnt(0)+barrier/tile.
// 8-slot XOR swizzle (slot ^ (row&7)), pre-applied on source, linear DMA dest.
__global__ __launch_bounds__(512, 2) void qgemm256(
    const __bf16* __restrict__ A, const __bf16* __restrict__ Bt, __bf16* __restrict__ C)
{
  __shared__ __align__(16) char ldsb[2 * 65536];  // 128 KB: per buf A[32K] B[32K]
  int lin = blockIdx.x;
  int xcd = lin & 7, idx = lin >> 3;         // 640 = 8 x 80 (bijective)
  int rt = xcd * 20 + (idx >> 2), ct = idx & 3;
  int t = threadIdx.x, l = t & 63, w = t >> 6;
  int wr = w >> 2, wc = w & 3;               // wave patch: 128 x 64
  f32x4 acc[8][4] = {};

  // staging: per tile 8 gloads/thread: p=0..3 A chunks c=t+512p, p=4..7 B.
  // chunk c: row = c>>3, slot = c&7 (16B each); source slot pre-swizzled
  // slot_g = (c&7) ^ ((c>>3)&7). LDS dest linear: c*16 (A), 32768 + c*16 (B).
  const char* gp[8];
  int dstp[8];
#pragma unroll
  for (int p = 0; p < 8; p++) {
    int c = t + 512 * (p & 3);
    int row = c >> 3;
    int sg = (c & 7) ^ (row & 7);
    if (p < 4) {
      gp[p] = (const char*)(A + (long)(rt * 256 + row) * 1024 + sg * 8);
      dstp[p] = w * 1024 + (p & 3) * 8192;
    } else {
      gp[p] = (const char*)(Bt + (long)(ct * 256 + row) * 1024 + sg * 8);
      dstp[p] = 32768 + w * 1024 + (p & 3) * 8192;
    }
  }

  int lr = l & 15, sl = l >> 4;
  // read byte offsets: row*128 + ((h*4 + sl) ^ (lr&7))*16
  int sx0 = (sl ^ (lr & 7)) * 16;        // h=0
  int sx1 = ((4 | sl) ^ (lr & 7)) * 16;  // h=1
  int arow = (wr * 128 + lr) * 128;            // + i*2048
  int brow = 32768 + (wc * 64 + lr) * 128;     // + j*2048

#define TILE(CUR, DOSTAGE)                                                             \
  {                                                                                    \
    const char* base = ldsb + (CUR) * 65536;                                           \
    char* sbase = ldsb + ((CUR) ^ 1) * 65536;                                          \
    bf16x8 bfr[4][2], af[2][2];                                                        \
    _Pragma("unroll") for (int j = 0; j < 4; j++) {                                    \
      bfr[j][0] = *(const bf16x8*)(base + brow + j * 2048 + sx0);                      \
      bfr[j][1] = *(const bf16x8*)(base + brow + j * 2048 + sx1);                      \
    }                                                                                  \
    _Pragma("unroll") for (int ph = 0; ph < 4; ph++) {                                 \
      if (DOSTAGE) {                                                                   \
        gload_lds16(gp[ph], sbase + dstp[ph]);                                         \
        gload_lds16(gp[ph + 4], sbase + dstp[ph + 4]);                                 \
      }                                                                                \
      _Pragma("unroll") for (int ii = 0; ii < 2; ii++) {                               \
        int i = ph * 2 + ii;                                                           \
        af[ii][0] = *(const bf16x8*)(base + arow + i * 2048 + sx0);                    \
        af[ii][1] = *(const bf16x8*)(base + arow + i * 2048 + sx1);                    \
      }                                                                                \
      __builtin_amdgcn_s_setprio(1);                                                   \
      _Pragma("unroll") for (int ii = 0; ii < 2; ii++)                                 \
        _Pragma("unroll") for (int j = 0; j < 4; j++) {                                \
          acc[ph * 2 + ii][j] = __builtin_amdgcn_mfma_f32_16x16x32_bf16(               \
              af[ii][0], bfr[j][0], acc[ph * 2 + ii][j], 0, 0, 0);                     \
          acc[ph * 2 + ii][j] = __builtin_amdgcn_mfma_f32_16x16x32_bf16(               \
              af[ii][1], bfr[j][1], acc[ph * 2 + ii][j], 0, 0, 0);                     \
        }                                                                              \
      __builtin_amdgcn_s_setprio(0);                                                   \
    }                                                                                  \
    if (DOSTAGE) {                                                                     \
      _Pragma("unroll") for (int p = 0; p < 8; p++) gp[p] += 128;                      \
    }                                                                                  \
  }

  // prologue: stage tile 0 into buf0 (advance pointers to tile 1)
  {
#pragma unroll
    for (int p = 0; p < 8; p++) {
      gload_lds16(gp[p], ldsb + dstp[p]);
      gp[p] += 128;
    }
  }
  asm volatile("s_waitcnt vmcnt(0)" ::: "memory");
  __builtin_amdgcn_s_barrier();
  for (int tt = 0; tt < 15; tt++) {  // tiles 0..14, staging 1..15
    TILE(tt & 1, 1)
    asm volatile("s_waitcnt vmcnt(0)" ::: "memory");
    __builtin_amdgcn_s_barrier();
  }
  TILE(1, 0)  // tile 15
#undef TILE

#pragma unroll
  for (int i = 0; i < 8; i++) {
    long mrow = (long)rt * 256 + wr * 128 + i * 16 + (sl << 2);
#pragma unroll
    for (int j = 0; j < 4; j++) {
      int n = ct * 256 + wc * 64 + j * 16 + lr;
#pragma unroll
      for (int r = 0; r < 4; r++)
        C[(mrow + r) * 1024 + n] = (__bf16)acc[i][j][r];
    }
  }
}

// ---------------------------------------------------------------------------
// gram: 20 cross-grams + lane-local softmax -> V. (r8-proven, 117us)
__global__ __launch_bounds__(256, 2) void gram_b16(
    const __bf16* __restrict__ Q, const __bf16* __restrict__ O, __bf16* __restrict__ V)
{
  __shared__ __align__(16) char ldsb[3 * 20480];  // 60 KB
  int bid = blockIdx.x;
  int xcd = bid & 7, idx = bid >> 3;          // 2048 = 8 XCD x 256 (bijective)
  int b = xcd * 4 + (idx >> 6);               // 4 batches per XCD
  int rem = idx & 63;
  int s1t = rem >> 3, s2t = rem & 7;          // s1t-major within batch
  int t = threadIdx.x, l = t & 63, w = t >> 6;
  int pr = w >> 1, pc = w & 1;
  f32x4 acc[20] = {};

  long qrow0 = (long)b * SS + s1t * 32;
  long orow0 = (long)b * SS + s2t * 32;
  int slog = (l & 3) ^ ((l >> 3) & 3);
  const char* gp0; const char* gp1; const char* gp2; const char* gp3; const char* gp4;
#define GP_INIT(GP, P)                                                                \
  {                                                                                   \
    int g = 4 * (P) + w;                                                              \
    int isQ = g < 10;                                                                 \
    int gg = isQ ? g : g - 10;                                                        \
    long row = (long)(gg >> 1) * (BB * SS) + (isQ ? qrow0 : orow0) + (g & 1) * 16 +   \
               (l >> 2);                                                              \
    GP = (const char*)((isQ ? Q : O) + row * HH + slog * 8);                          \
  }
  GP_INIT(gp0, 0) GP_INIT(gp1, 1) GP_INIT(gp2, 2) GP_INIT(gp3, 3) GP_INIT(gp4, 4)
#undef GP_INIT
  int g0 = w, g1 = 4 + w, g2 = 8 + w, g3 = 12 + w, g4 = 16 + w;

#define STAGE(BB_)                                                      \
  {                                                                     \
    char* base = ldsb + (BB_) * 20480;                                  \
    gload_lds16(gp0, base + g0 * 1024); gp0 += 64;                      \
    gload_lds16(gp1, base + g1 * 1024); gp1 += 64;                      \
    gload_lds16(gp2, base + g2 * 1024); gp2 += 64;                      \
    gload_lds16(gp3, base + g3 * 1024); gp3 += 64;                      \
    gload_lds16(gp4, base + g4 * 1024); gp4 += 64;                      \
  }

  int lr = l & 15, sl = l >> 4;
  int swz = (sl ^ ((lr >> 1) & 3)) * 16;
  int qoff = (pr * 16 + lr) * 64 + swz;
  int ooff = 10240 + (pc * 16 + lr) * 64 + swz;

#define COMPUTE(BB_)                                                                   \
  {                                                                                    \
    const char* base = ldsb + (BB_) * 20480;                                           \
    bf16x8 qf[5], of[5];                                                               \
    _Pragma("unroll") for (int m = 0; m < 5; m++) {                                    \
      qf[m] = *(const bf16x8*)(base + m * 2048 + qoff);                                \
      of[m] = *(const bf16x8*)(base + m * 2048 + ooff);                                \
    }                                                                                  \
    __builtin_amdgcn_s_setprio(1);                                                     \
    _Pragma("unroll") for (int i = 0; i < 5; i++) {                                    \
      _Pragma("unroll") for (int n = 0; n < 5; n++) {                                  \
        if (n != i)                                                                    \
          acc[PAIR(i, n)] =                                                            \
              __builtin_amdgcn_mfma_f32_16x16x32_bf16(qf[i], of[n], acc[PAIR(i, n)],   \
                                                      0, 0, 0);                        \
      }                                                                                \
    }                                                                                  \
    __builtin_amdgcn_s_setprio(0);                                                     \
  }

#define STEP(CUR, STG)                                          \
  asm volatile("s_waitcnt vmcnt(5)" ::: "memory");              \
  __builtin_amdgcn_s_barrier();                                 \
  STAGE(STG);                                                   \
  COMPUTE(CUR);

  STAGE(0)
  STAGE(1)
  for (int it = 0; it < 10; it++) {
    STEP(0, 2)
    STEP(1, 0)
    STEP(2, 1)
  }
  asm volatile("s_waitcnt vmcnt(5)" ::: "memory");
  __builtin_amdgcn_s_barrier();
  COMPUTE(0)
  asm volatile("s_waitcnt vmcnt(0)" ::: "memory");
  __builtin_amdgcn_s_barrier();
  COMPUTE(1)
#undef STEP
#undef COMPUTE
#undef STAGE

  int s1g = s1t * 32 + pr * 16 + ((l >> 4) << 2);
  int s2g = s2t * 32 + pc * 16 + (l & 15);
#pragma unroll
  for (int r = 0; r < 4; r++) {
    float vacc[5] = {0.f, 0.f, 0.f, 0.f, 0.f};
#pragma unroll
    for (int i = 0; i < 5; i++) {
      float gg[5];
      float mx = -3.0e38f;
#pragma unroll
      for (int n = 0; n < 5; n++)
        if (n != i) { gg[n] = acc[PAIR(i, n)][r]; mx = fmaxf(mx, gg[n]); }
      float ee[5], ssum = 0.f;
#pragma unroll
      for (int n = 0; n < 5; n++)
        if (n != i) { ee[n] = __expf(gg[n] - mx); ssum += ee[n]; }
      float inv = 1.0f / ssum;
#pragma unroll
      for (int n = 0; n < 5; n++)
        if (n != i) vacc[n] += ee[n] * inv;
    }
#pragma unroll
    for (int n = 0; n < 5; n++)
      V[((long)(n * 32 + b) * 256 + s1g + r) * 256 + s2g] = (__bf16)vacc[n];
  }
}

// ---------------------------------------------------------------------------
// out = 0.5 * sum_n V_n @ o_n (per batch). A: V rows (bf16, s2-contig).
// B: Obf bf16 (s2 x h), transposed in LDS via 4x4 register sub-blocks.
__global__ __launch_bounds__(256) void pvgemm(
    const __bf16* __restrict__ Vb, const __bf16* __restrict__ Obf, float* __restrict__ out)
{
  __shared__ __bf16 smA[128][40];
  __shared__ __bf16 smB[128][40];
  int bid = blockIdx.x;
  int b = bid >> 4, s1t = (bid >> 3) & 1, ht = bid & 7;
  int t = threadIdx.x, l = t & 63, w = t >> 6;
  int wm = w >> 1, wn = w & 1;
  f32x4 acc[4][4] = {};
#pragma unroll
  for (int n = 0; n < 5; n++) {
    const __bf16* On = Obf + (long)n * BB * SS * HH;
    for (int st2 = 0; st2 < 8; st2++) {
      int s20 = st2 * 32;
#pragma unroll
      for (int p = 0; p < 2; p++) {
        int c = t + p * 256;
        int row = c >> 2, sl = c & 3;
        *(bf16x8*)&smA[row][sl * 8] =
            *(const bf16x8*)(Vb + (long)(n * BB + b) * SS * SS + (long)(s1t * 128 + row) * SS +
                             s20 + sl * 8);
      }
      {
        int h4 = (t & 31) * 4, s2q = (t >> 5) * 4;
        const __bf16* src = On + ((long)b * 256 + s20 + s2q) * 1024 + ht * 128 + h4;
        bf16x4 v0 = *(const bf16x4*)(src);
        bf16x4 v1 = *(const bf16x4*)(src + 1024);
        bf16x4 v2 = *(const bf16x4*)(src + 2048);
        bf16x4 v3 = *(const bf16x4*)(src + 3072);
        bf16x4 c0, c1, c2, c3;
        c0[0] = v0[0]; c0[1] = v1[0]; c0[2] = v2[0]; c0[3] = v3[0];
        c1[0] = v0[1]; c1[1] = v1[1]; c1[2] = v2[1]; c1[3] = v3[1];
        c2[0] = v0[2]; c2[1] = v1[2]; c2[2] = v2[2]; c2[3] = v3[2];
        c3[0] = v0[3]; c3[1] = v1[3]; c3[2] = v2[3]; c3[3] = v3[3];
        *(bf16x4*)&smB[h4 + 0][s2q] = c0;
        *(bf16x4*)&smB[h4 + 1][s2q] = c1;
        *(bf16x4*)&smB[h4 + 2][s2q] = c2;
        *(bf16x4*)&smB[h4 + 3][s2q] = c3;
      }
      __syncthreads();
      bf16x8 af[4], bfr[4];
      int sl = l >> 4, lr = l & 15;
#pragma unroll
      for (int i = 0; i < 4; i++) {
        af[i]  = *(const bf16x8*)&smA[wm * 64 + i * 16 + lr][sl * 8];
        bfr[i] = *(const bf16x8*)&smB[wn * 64 + i * 16 + lr][sl * 8];
      }
#pragma unroll
      for (int i = 0; i < 4; i++)
#pragma unroll
        for (int j = 0; j < 4; j++)
          acc[i][j] = __builtin_amdgcn_mfma_f32_16x16x32_bf16(af[i], bfr[j], acc[i][j], 0, 0, 0);
      __syncthreads();
    }
  }
#pragma unroll
  for (int i = 0; i < 4; i++) {
    int m = s1t * 128 + wm * 64 + i * 16 + ((l >> 4) << 2);
#pragma unroll
    for (int j = 0; j < 4; j++) {
      int n = ht * 128 + wn * 64 + j * 16 + (l & 15);
#pragma unroll
      for (int r = 0; r < 4; r++)
        out[(long)(b * SS + m + r) * HH + n] = 0.5f * acc[i][j][r];
    }
  }
}

// ---------------------------------------------------------------------------
extern "C" void kernel_launch(void* const* d_in, const int* in_sizes, int n_in,
                              void* d_out, int out_size, void* d_ws, size_t ws_size,
                              hipStream_t stream)
{
  const size_t SZ_W = (size_t)HH * HH * 2;           //  2 MB
  const size_t SZ_Q = (size_t)5 * BB * SS * HH * 2;  // 84 MB
  const size_t SZ_V = (size_t)5 * BB * SS * SS * 2;  // 21 MB
  const size_t SZ_O = (size_t)5 * BB * SS * HH * 2;  // 84 MB
  const size_t NEED = SZ_W + SZ_Q + SZ_V + SZ_O;     // 191 MB (proven available r4)
  if (ws_size < NEED) {
    canary<<<1, 1, 0, stream>>>((float*)d_out, (float)(ws_size >> 20));
    return;
  }
  char* ws = (char*)d_ws;
  __bf16* Wt  = (__bf16*)ws;
  __bf16* Qb  = (__bf16*)(ws + SZ_W);
  __bf16* Vb  = (__bf16*)(ws + SZ_W + SZ_Q);
  __bf16* Obf = (__bf16*)(ws + SZ_W + SZ_Q + SZ_V);
  const float* o0 = (const float*)d_in[0];
  const float* o1 = (const float*)d_in[1];
  const float* o2 = (const float*)d_in[2];
  const float* o3 = (const float*)d_in[3];
  const float* o4 = (const float*)d_in[4];

  cast_trW<<<256, 256, 0, stream>>>((const float*)d_in[5], Wt);
  cast_all<<<5 * 4096, 256, 0, stream>>>(o0, o1, o2, o3, o4, Obf);
  qgemm256<<<640, 512, 0, stream>>>(Obf, Wt, Qb);
  gram_b16<<<2048, 256, 0, stream>>>(Qb, Obf, Vb);
  pvgemm<<<512, 256, 0, stream>>>(Vb, Obf, (float*)d_out);
}

// Round 14
// 262.056 us; speedup vs baseline: 1.4555x; 1.0682x over previous
//
#include <hip/hip_runtime.h>
#include <hip/hip_bf16.h>
#include <stdint.h>

// Problem: b=32, s=256, h=1024, 5 options.
// out = 0.5 * sum_n V_n @ o_n,  V_n = sum_{i!=n} softmax_k(q_i . o_k)_n,  q_i = o_i @ W
// bias is softmax-shift-invariant -> ignored.
// Round 14: gram64 — per-wave 16x32 patch (8 waves, 64x64 block). read:MFMA
// 0.375 vs 0.5; per-output LDS traffic 0.66x -> MFMA-bound (~83us floor).
// acc 160 VGPR + per-half O-frags (no spill). r8 staging protocol verbatim.
// qgemm256/pvgemm/casts frozen.

#define BB 32
#define SS 256
#define HH 1024

typedef __attribute__((ext_vector_type(4))) float f32x4;
typedef __attribute__((ext_vector_type(8))) __bf16 bf16x8;
typedef __attribute__((ext_vector_type(4))) __bf16 bf16x4;

__device__ constexpr int PAIR(int i, int n) { return i * 4 + (n > i ? n - 1 : n); }

__device__ __forceinline__ void gload_lds16(const void* g, void* l) {
  __builtin_amdgcn_global_load_lds((const __attribute__((address_space(1))) void*)g,
                                   (__attribute__((address_space(3))) void*)l, 16, 0, 0);
}

__global__ void canary(float* out, float v) { out[0] = v; }

// ---------------------------------------------------------------------------
// fp32 -> bf16 flat cast of the 5 options into Obf[m][b][s][h].
__global__ __launch_bounds__(256) void cast_all(
    const float* p0, const float* p1, const float* p2, const float* p3, const float* p4,
    __bf16* __restrict__ dst)
{
  int m = blockIdx.x >> 12;
  long off = ((long)(blockIdx.x & 4095) * 256 + threadIdx.x) * 8;
  const float* src = m == 0 ? p0 : m == 1 ? p1 : m == 2 ? p2 : m == 3 ? p3 : p4;
  float4 v0 = *(const float4*)(src + off);
  float4 v1 = *(const float4*)(src + off + 4);
  bf16x8 h;
  h[0] = (__bf16)v0.x; h[1] = (__bf16)v0.y; h[2] = (__bf16)v0.z; h[3] = (__bf16)v0.w;
  h[4] = (__bf16)v1.x; h[5] = (__bf16)v1.y; h[6] = (__bf16)v1.z; h[7] = (__bf16)v1.w;
  *(bf16x8*)(dst + (long)m * BB * SS * HH + off) = h;
}

// ---------------------------------------------------------------------------
// W (1024x1024 fp32) -> Wt (bf16, transposed). 64x64 tiles, grid 256.
__global__ __launch_bounds__(256) void cast_trW(const float* __restrict__ src,
                                                __bf16* __restrict__ dstT)
{
  __shared__ __bf16 tile[64][72];
  int ct = blockIdx.x & 15, rt = blockIdx.x >> 4;
  const float* s = src + (long)(rt * 64) * 1024 + ct * 64;
  int t = threadIdx.x;
#pragma unroll
  for (int p = 0; p < 4; p++) {
    int c = t + p * 256;
    int row = c >> 4, c4 = c & 15;
    float4 v = *(const float4*)(s + (long)row * 1024 + c4 * 4);
    bf16x4 h;
    h[0] = (__bf16)v.x; h[1] = (__bf16)v.y; h[2] = (__bf16)v.z; h[3] = (__bf16)v.w;
    *(bf16x4*)&tile[row][c4 * 4] = h;
  }
  __syncthreads();
#pragma unroll
  for (int p = 0; p < 4; p++) {
    int c = t + p * 256;
    int hr = c >> 4, s4 = c & 15;
    bf16x4 h;
    h[0] = tile[s4 * 4 + 0][hr];
    h[1] = tile[s4 * 4 + 1][hr];
    h[2] = tile[s4 * 4 + 2][hr];
    h[3] = tile[s4 * 4 + 3][hr];
    *(bf16x4*)(dstT + (long)(ct * 64 + hr) * 1024 + rt * 64 + s4 * 4) = h;
  }
}

// ---------------------------------------------------------------------------
// qgemm256: Q = Obf @ Wt. 256x256 tile, 512 thr, 8 waves, BK=64, 2x64KB dbuf,
// 4-phase interleave, one vmcnt(0)+barrier per tile. (r13, frozen)
__global__ __launch_bounds__(512, 2) void qgemm256(
    const __bf16* __restrict__ A, const __bf16* __restrict__ Bt, __bf16* __restrict__ C)
{
  __shared__ __align__(16) char ldsb[2 * 65536];
  int lin = blockIdx.x;
  int xcd = lin & 7, idx = lin >> 3;
  int rt = xcd * 20 + (idx >> 2), ct = idx & 3;
  int t = threadIdx.x, l = t & 63, w = t >> 6;
  int wr = w >> 2, wc = w & 3;
  f32x4 acc[8][4] = {};

  const char* gp[8];
  int dstp[8];
#pragma unroll
  for (int p = 0; p < 8; p++) {
    int c = t + 512 * (p & 3);
    int row = c >> 3;
    int sg = (c & 7) ^ (row & 7);
    if (p < 4) {
      gp[p] = (const char*)(A + (long)(rt * 256 + row) * 1024 + sg * 8);
      dstp[p] = w * 1024 + (p & 3) * 8192;
    } else {
      gp[p] = (const char*)(Bt + (long)(ct * 256 + row) * 1024 + sg * 8);
      dstp[p] = 32768 + w * 1024 + (p & 3) * 8192;
    }
  }

  int lr = l & 15, sl = l >> 4;
  int sx0 = (sl ^ (lr & 7)) * 16;
  int sx1 = ((4 | sl) ^ (lr & 7)) * 16;
  int arow = (wr * 128 + lr) * 128;
  int brow = 32768 + (wc * 64 + lr) * 128;

#define TILE(CUR, DOSTAGE)                                                             \
  {                                                                                    \
    const char* base = ldsb + (CUR) * 65536;                                           \
    char* sbase = ldsb + ((CUR) ^ 1) * 65536;                                          \
    bf16x8 bfr[4][2], af[2][2];                                                        \
    _Pragma("unroll") for (int j = 0; j < 4; j++) {                                    \
      bfr[j][0] = *(const bf16x8*)(base + brow + j * 2048 + sx0);                      \
      bfr[j][1] = *(const bf16x8*)(base + brow + j * 2048 + sx1);                      \
    }                                                                                  \
    _Pragma("unroll") for (int ph = 0; ph < 4; ph++) {                                 \
      if (DOSTAGE) {                                                                   \
        gload_lds16(gp[ph], sbase + dstp[ph]);                                         \
        gload_lds16(gp[ph + 4], sbase + dstp[ph + 4]);                                 \
      }                                                                                \
      _Pragma("unroll") for (int ii = 0; ii < 2; ii++) {                               \
        int i = ph * 2 + ii;                                                           \
        af[ii][0] = *(const bf16x8*)(base + arow + i * 2048 + sx0);                    \
        af[ii][1] = *(const bf16x8*)(base + arow + i * 2048 + sx1);                    \
      }                                                                                \
      __builtin_amdgcn_s_setprio(1);                                                   \
      _Pragma("unroll") for (int ii = 0; ii < 2; ii++)                                 \
        _Pragma("unroll") for (int j = 0; j < 4; j++) {                                \
          acc[ph * 2 + ii][j] = __builtin_amdgcn_mfma_f32_16x16x32_bf16(               \
              af[ii][0], bfr[j][0], acc[ph * 2 + ii][j], 0, 0, 0);                     \
          acc[ph * 2 + ii][j] = __builtin_amdgcn_mfma_f32_16x16x32_bf16(               \
              af[ii][1], bfr[j][1], acc[ph * 2 + ii][j], 0, 0, 0);                     \
        }                                                                              \
      __builtin_amdgcn_s_setprio(0);                                                   \
    }                                                                                  \
    if (DOSTAGE) {                                                                     \
      _Pragma("unroll") for (int p = 0; p < 8; p++) gp[p] += 128;                      \
    }                                                                                  \
  }

  {
#pragma unroll
    for (int p = 0; p < 8; p++) {
      gload_lds16(gp[p], ldsb + dstp[p]);
      gp[p] += 128;
    }
  }
  asm volatile("s_waitcnt vmcnt(0)" ::: "memory");
  __builtin_amdgcn_s_barrier();
  for (int tt = 0; tt < 15; tt++) {
    TILE(tt & 1, 1)
    asm volatile("s_waitcnt vmcnt(0)" ::: "memory");
    __builtin_amdgcn_s_barrier();
  }
  TILE(1, 0)
#undef TILE

#pragma unroll
  for (int i = 0; i < 8; i++) {
    long mrow = (long)rt * 256 + wr * 128 + i * 16 + (sl << 2);
#pragma unroll
    for (int j = 0; j < 4; j++) {
      int n = ct * 256 + wc * 64 + j * 16 + lr;
#pragma unroll
      for (int r = 0; r < 4; r++)
        C[(mrow + r) * 1024 + n] = (__bf16)acc[i][j][r];
    }
  }
}

// ---------------------------------------------------------------------------
// gram64: 20 cross-grams + lane-local softmax -> V.
// 512 thr, 8 waves (4x2); wave patch 16(s1) x 32(s2); block 64x64.
// Per K32-step: 5 Q-frag reads + 2x5 O-frag reads feed 2x20 MFMA.
// Staging: 40KB/step, 5 uniform gloads/thread, 3 buffers, vmcnt(5),
// one barrier/step (r8 protocol). XOR swizzle both sides (r8 algebra).
__global__ __launch_bounds__(512, 2) void gram64(
    const __bf16* __restrict__ Q, const __bf16* __restrict__ O, __bf16* __restrict__ V)
{
  __shared__ __align__(16) char ldsb[3 * 40960];  // 120 KB
  int bid = blockIdx.x;
  int xcd = bid & 7, idx = bid >> 3;   // 512 = 8 XCD x 64 (bijective)
  int b = xcd * 4 + (idx >> 4);        // 4 batches per XCD
  int rem = idx & 15;
  int s1t = rem >> 2, s2t = rem & 3;   // s1t-major within batch
  int t = threadIdx.x, l = t & 63, w = t >> 6;
  int wr = w >> 1, wc = w & 1;         // wave = s1 [wr*16,+16) x s2 [wc*32,+32)
  f32x4 acc[20][2] = {};               // [pair][s2-half], 160 VGPR

  // staging: thread t, p=0..4: chunk c = t + 512p in [0,2560).
  // c<1280: Q (opt m=c>>8, row rr=(c>>2)&63, slot c&3); else O (c-1280).
  // source slot pre-swizzled: (c&3) ^ ((c>>3)&3). 1280 = wave-aligned split.
  const char* gp[5];
#pragma unroll
  for (int p = 0; p < 5; p++) {
    int c = t + 512 * p;
    int isQ = c < 1280;
    int cc = isQ ? c : c - 1280;
    int m = cc >> 8, rr = (cc >> 2) & 63;
    int sg = (cc & 3) ^ ((cc >> 3) & 3);
    long row = (long)m * (BB * SS) + (long)b * SS + (isQ ? s1t : s2t) * 64 + rr;
    gp[p] = (const char*)((isQ ? Q : O) + row * HH + sg * 8);
  }
  int dstb = (t & ~63) << 4;  // wave-uniform; chunk p at +p*8192; HW adds lane*16

#define STAGE(BUF)                                                      \
  {                                                                     \
    char* base = ldsb + (BUF) * 40960 + dstb;                           \
    _Pragma("unroll") for (int p = 0; p < 5; p++) {                     \
      gload_lds16(gp[p], base + p * 8192);                              \
      gp[p] += 64;                                                      \
    }                                                                   \
  }

  // read offsets (same XOR swizzle as source): Q at m*4096, O at 20480+m*4096
  int lr = l & 15, sl = l >> 4;
  int swz = (sl ^ ((lr >> 1) & 3)) * 16;
  int qoff = (wr * 16 + lr) * 64 + swz;
  int ooff0 = 20480 + (wc * 32 + lr) * 64 + swz;
  int ooff1 = ooff0 + 1024;  // +16 rows

#define COMPUTE(BUF)                                                                   \
  {                                                                                    \
    const char* base = ldsb + (BUF) * 40960;                                           \
    bf16x8 qf[5], of[5];                                                               \
    _Pragma("unroll") for (int m = 0; m < 5; m++)                                      \
      qf[m] = *(const bf16x8*)(base + m * 4096 + qoff);                                \
    _Pragma("unroll") for (int m = 0; m < 5; m++)                                      \
      of[m] = *(const bf16x8*)(base + m * 4096 + ooff0);                               \
    __builtin_amdgcn_s_setprio(1);                                                     \
    _Pragma("unroll") for (int i = 0; i < 5; i++) {                                    \
      _Pragma("unroll") for (int n = 0; n < 5; n++) {                                  \
        if (n != i)                                                                    \
          acc[PAIR(i, n)][0] = __builtin_amdgcn_mfma_f32_16x16x32_bf16(                \
              qf[i], of[n], acc[PAIR(i, n)][0], 0, 0, 0);                              \
      }                                                                                \
    }                                                                                  \
    __builtin_amdgcn_s_setprio(0);                                                     \
    _Pragma("unroll") for (int m = 0; m < 5; m++)                                      \
      of[m] = *(const bf16x8*)(base + m * 4096 + ooff1);                               \
    __builtin_amdgcn_s_setprio(1);                                                     \
    _Pragma("unroll") for (int i = 0; i < 5; i++) {                                    \
      _Pragma("unroll") for (int n = 0; n < 5; n++) {                                  \
        if (n != i)                                                                    \
          acc[PAIR(i, n)][1] = __builtin_amdgcn_mfma_f32_16x16x32_bf16(                \
              qf[i], of[n], acc[PAIR(i, n)][1], 0, 0, 0);                              \
      }                                                                                \
    }                                                                                  \
    __builtin_amdgcn_s_setprio(0);                                                     \
  }

#define STEP(CUR, STG)                                          \
  asm volatile("s_waitcnt vmcnt(5)" ::: "memory");              \
  __builtin_amdgcn_s_barrier();                                 \
  STAGE(STG);                                                   \
  COMPUTE(CUR);

  STAGE(0)
  STAGE(1)
  for (int it = 0; it < 10; it++) {  // K32-steps 0..29, staging 2..31
    STEP(0, 2)
    STEP(1, 0)
    STEP(2, 1)
  }
  asm volatile("s_waitcnt vmcnt(5)" ::: "memory");  // step 30
  __builtin_amdgcn_s_barrier();
  COMPUTE(0)
  asm volatile("s_waitcnt vmcnt(0)" ::: "memory");  // step 31
  __builtin_amdgcn_s_barrier();
  COMPUTE(1)
#undef STEP
#undef COMPUTE
#undef STAGE

  // epilogue: lane-local softmax over 4 options; C layout: s2 = l&15 (col),
  // s1 = (l>>4)*4 + r (row).
  int s1b = s1t * 64 + wr * 16 + sl * 4;
  int s2b = s2t * 64 + wc * 32 + lr;
#pragma unroll
  for (int h = 0; h < 2; h++) {
#pragma unroll
    for (int r = 0; r < 4; r++) {
      float vacc[5] = {0.f, 0.f, 0.f, 0.f, 0.f};
#pragma unroll
      for (int i = 0; i < 5; i++) {
        float gg[5];
        float mx = -3.0e38f;
#pragma unroll
        for (int n = 0; n < 5; n++)
          if (n != i) { gg[n] = acc[PAIR(i, n)][h][r]; mx = fmaxf(mx, gg[n]); }
        float ee[5], ssum = 0.f;
#pragma unroll
        for (int n = 0; n < 5; n++)
          if (n != i) { ee[n] = __expf(gg[n] - mx); ssum += ee[n]; }
        float inv = 1.0f / ssum;
#pragma unroll
        for (int n = 0; n < 5; n++)
          if (n != i) vacc[n] += ee[n] * inv;
      }
      int s1 = s1b + r, s2 = s2b + h * 16;
#pragma unroll
      for (int n = 0; n < 5; n++)
        V[((long)(n * BB + b) * SS + s1) * SS + s2] = (__bf16)vacc[n];
    }
  }
}

// ---------------------------------------------------------------------------
// out = 0.5 * sum_n V_n @ o_n (per batch). A: V rows (bf16, s2-contig).
// B: Obf bf16 (s2 x h), transposed in LDS via 4x4 register sub-blocks.
__global__ __launch_bounds__(256) void pvgemm(
    const __bf16* __restrict__ Vb, const __bf16* __restrict__ Obf, float* __restrict__ out)
{
  __shared__ __bf16 smA[128][40];
  __shared__ __bf16 smB[128][40];
  int bid = blockIdx.x;
  int b = bid >> 4, s1t = (bid >> 3) & 1, ht = bid & 7;
  int t = threadIdx.x, l = t & 63, w = t >> 6;
  int wm = w >> 1, wn = w & 1;
  f32x4 acc[4][4] = {};
#pragma unroll
  for (int n = 0; n < 5; n++) {
    const __bf16* On = Obf + (long)n * BB * SS * HH;
    for (int st2 = 0; st2 < 8; st2++) {
      int s20 = st2 * 32;
#pragma unroll
      for (int p = 0; p < 2; p++) {
        int c = t + p * 256;
        int row = c >> 2, sl = c & 3;
        *(bf16x8*)&smA[row][sl * 8] =
            *(const bf16x8*)(Vb + (long)(n * BB + b) * SS * SS + (long)(s1t * 128 + row) * SS +
                             s20 + sl * 8);
      }
      {
        int h4 = (t & 31) * 4, s2q = (t >> 5) * 4;
        const __bf16* src = On + ((long)b * 256 + s20 + s2q) * 1024 + ht * 128 + h4;
        bf16x4 v0 = *(const bf16x4*)(src);
        bf16x4 v1 = *(const bf16x4*)(src + 1024);
        bf16x4 v2 = *(const bf16x4*)(src + 2048);
        bf16x4 v3 = *(const bf16x4*)(src + 3072);
        bf16x4 c0, c1, c2, c3;
        c0[0] = v0[0]; c0[1] = v1[0]; c0[2] = v2[0]; c0[3] = v3[0];
        c1[0] = v0[1]; c1[1] = v1[1]; c1[2] = v2[1]; c1[3] = v3[1];
        c2[0] = v0[2]; c2[1] = v1[2]; c2[2] = v2[2]; c2[3] = v3[2];
        c3[0] = v0[3]; c3[1] = v1[3]; c3[2] = v2[3]; c3[3] = v3[3];
        *(bf16x4*)&smB[h4 + 0][s2q] = c0;
        *(bf16x4*)&smB[h4 + 1][s2q] = c1;
        *(bf16x4*)&smB[h4 + 2][s2q] = c2;
        *(bf16x4*)&smB[h4 + 3][s2q] = c3;
      }
      __syncthreads();
      bf16x8 af[4], bfr[4];
      int sl = l >> 4, lr = l & 15;
#pragma unroll
      for (int i = 0; i < 4; i++) {
        af[i]  = *(const bf16x8*)&smA[wm * 64 + i * 16 + lr][sl * 8];
        bfr[i] = *(const bf16x8*)&smB[wn * 64 + i * 16 + lr][sl * 8];
      }
#pragma unroll
      for (int i = 0; i < 4; i++)
#pragma unroll
        for (int j = 0; j < 4; j++)
          acc[i][j] = __builtin_amdgcn_mfma_f32_16x16x32_bf16(af[i], bfr[j], acc[i][j], 0, 0, 0);
      __syncthreads();
    }
  }
#pragma unroll
  for (int i = 0; i < 4; i++) {
    int m = s1t * 128 + wm * 64 + i * 16 + ((l >> 4) << 2);
#pragma unroll
    for (int j = 0; j < 4; j++) {
      int n = ht * 128 + wn * 64 + j * 16 + (l & 15);
#pragma unroll
      for (int r = 0; r < 4; r++)
        out[(long)(b * SS + m + r) * HH + n] = 0.5f * acc[i][j][r];
    }
  }
}

// ---------------------------------------------------------------------------
extern "C" void kernel_launch(void* const* d_in, const int* in_sizes, int n_in,
                              void* d_out, int out_size, void* d_ws, size_t ws_size,
                              hipStream_t stream)
{
  const size_t SZ_W = (size_t)HH * HH * 2;           //  2 MB
  const size_t SZ_Q = (size_t)5 * BB * SS * HH * 2;  // 84 MB
  const size_t SZ_V = (size_t)5 * BB * SS * SS * 2;  // 21 MB
  const size_t SZ_O = (size_t)5 * BB * SS * HH * 2;  // 84 MB
  const size_t NEED = SZ_W + SZ_Q + SZ_V + SZ_O;     // 191 MB (proven available r4)
  if (ws_size < NEED) {
    canary<<<1, 1, 0, stream>>>((float*)d_out, (float)(ws_size >> 20));
    return;
  }
  char* ws = (char*)d_ws;
  __bf16* Wt  = (__bf16*)ws;
  __bf16* Qb  = (__bf16*)(ws + SZ_W);
  __bf16* Vb  = (__bf16*)(ws + SZ_W + SZ_Q);
  __bf16* Obf = (__bf16*)(ws + SZ_W + SZ_Q + SZ_V);
  const float* o0 = (const float*)d_in[0];
  const float* o1 = (const float*)d_in[1];
  const float* o2 = (const float*)d_in[2];
  const float* o3 = (const float*)d_in[3];
  const float* o4 = (const float*)d_in[4];

  cast_trW<<<256, 256, 0, stream>>>((const float*)d_in[5], Wt);
  cast_all<<<5 * 4096, 256, 0, stream>>>(o0, o1, o2, o3, o4, Obf);
  qgemm256<<<640, 512, 0, stream>>>(Obf, Wt, Qb);
  gram64<<<512, 512, 0, stream>>>(Qb, Obf, Vb);
  pvgemm<<<512, 256, 0, stream>>>(Vb, Obf, (float*)d_out);
}